// Round 3
// baseline (594.029 us; speedup 1.0000x reference)
//
#include <hip/hip_runtime.h>

#define C_OUT  32
#define PS     16
#define KB     288          // 3*3*32 input capsules per patch
#define NITER  3
#define EPSL   1e-6f
#define LAM    0.001f
#define OH     12
#define OW     12
#define NPOS   576          // 4*12*12
#define MU_SZ  (NPOS*C_OUT*PS)
#define NG     16           // k-groups (one per 32-lane half-wave)
#define KPG    (KB/NG)      // 18 k's per thread

// v[k,c,i,l] = sum_j xp[k,i,j] * w[k,c,j,l]  — full 4x4 matrix per (k,c) in registers.
__device__ __forceinline__ void compute_v(const float* __restrict__ xp,
                                          const float* __restrict__ w,
                                          int k, int c, float* __restrict__ va) {
    const float4* xk = (const float4*)(xp + (k << 4));
    float4 x0 = xk[0], x1 = xk[1], x2 = xk[2], x3 = xk[3];   // row i over j
    const float4* wr = (const float4*)(w + (((k << 5) + c) << 4));
    float4 w0 = wr[0], w1 = wr[1], w2 = wr[2], w3 = wr[3];   // row j over l
#define VROW(i, xi) \
    va[4*i+0] = fmaf(xi.x, w0.x, fmaf(xi.y, w1.x, fmaf(xi.z, w2.x, xi.w * w3.x))); \
    va[4*i+1] = fmaf(xi.x, w0.y, fmaf(xi.y, w1.y, fmaf(xi.z, w2.y, xi.w * w3.y))); \
    va[4*i+2] = fmaf(xi.x, w0.z, fmaf(xi.y, w1.z, fmaf(xi.z, w2.z, xi.w * w3.z))); \
    va[4*i+3] = fmaf(xi.x, w0.w, fmaf(xi.y, w1.w, fmaf(xi.z, w2.w, xi.w * w3.w)));
    VROW(0, x0) VROW(1, x1) VROW(2, x2) VROW(3, x3)
#undef VROW
}

__global__ __launch_bounds__(512, 6)   // 6 waves/SIMD -> 3 blocks/CU; VGPR <= ~85
void emcaps_kernel(const float* __restrict__ x, const float* __restrict__ a,
                   const float* __restrict__ w, const float* __restrict__ beta_u,
                   const float* __restrict__ beta_a, float* __restrict__ out) {
    __shared__ __align__(16) float xp[KB * PS];   // 18 KB patch poses [k][16]
    __shared__ float a_lds[KB];                   // input activations (pre-scaled 1/C)
    __shared__ float buf[8][32][16];              // 16 KB: m1 partials, then m2 partials
    __shared__ float rsp[8][32];                  // partial r_sum
    __shared__ float mu_s[32][16];                // mu    [c][e ^ (c&15)]
    __shared__ float is_s[32][16];                // 0.5/sigma^2, same swizzle
    __shared__ float cst_s[32];                   // log(a_out) - sum_e 0.5 log sigma^2
    __shared__ float ao_s[32];                    // a_out

    const int t  = threadIdx.x;       // 512 threads
    const int g  = t >> 5;            // k-group 0..15  (E-step view)
    const int c  = t & 31;            // output capsule (E-step view)
    const int oc = t >> 4;            // capsule 0..31  (M-step view)
    const int oe = t & 15;            // pose elem      (M-step view)

    const int pos = blockIdx.x;
    const int bb  = pos / (OH * OW);
    const int rem = pos % (OH * OW);
    const int hh  = rem / OW;
    const int ww  = rem % OW;

    // ---- stage 3x3 patch into LDS (9 contiguous 2 KB rows, coalesced float4)
    const float4* x4  = (const float4*)x;
    float4*       xp4 = (float4*)xp;
    for (int u = t; u < KB * PS / 4; u += 512) {
        int pc = u >> 7, r = u & 127;
        int ki = pc / 3, kj = pc % 3;
        long src = (((long)(bb * 14 + hh + ki)) * 14 + (ww + kj)) * 128;
        xp4[u] = x4[src + r];
    }
    if (t < KB) {
        int pc = t >> 5, bi = t & 31;
        int ki = pc / 3, kj = pc % 3;
        a_lds[t] = a[(((bb * 14 + hh + ki)) * 14 + (ww + kj)) * 32 + bi] * (1.0f / C_OUT);
    }
    __syncthreads();

    const float buC = beta_u[oc];     // M-step view constants
    const float baC = beta_a[oc];

    float muR[16], isR[16];           // E-step per-c state (registers)
    float cstC = 0.f, aoC = 0.f;

    for (int it = 0; it < NITER; ++it) {
        float m1[16], m2[16], rs = 0.f;
        #pragma unroll
        for (int e = 0; e < 16; ++e) { m1[e] = 0.f; m2[e] = 0.f; }

        if (it == 0) {
            #pragma unroll 2
            for (int kk = 0; kk < KPG; ++kk) {
                int k = g * KPG + kk;
                float va[16];
                compute_v(xp, w, k, c, va);
                float r = a_lds[k];               // already scaled by 1/C
                rs += r;
                #pragma unroll
                for (int e = 0; e < 16; ++e) {
                    float rv = r * va[e];
                    m1[e] += rv;
                    m2[e] = fmaf(rv, va[e], m2[e]);
                }
            }
        } else {
            #pragma unroll 2
            for (int kk = 0; kk < KPG; ++kk) {
                int k = g * KPG + kk;
                float va[16];
                compute_v(xp, w, k, c, va);
                // ln-term: fully lane-local (no shuffles)
                float acc = 0.f;
                #pragma unroll
                for (int e = 0; e < 16; ++e) {
                    float d = va[e] - muR[e];
                    acc = fmaf(d * d, isR[e], acc);
                }
                float ln = cstC - acc;
                // softmax over c: 32-lane butterfly (lane bits 0..4)
                float mx = ln;
                mx = fmaxf(mx, __shfl_xor(mx, 16));
                mx = fmaxf(mx, __shfl_xor(mx, 8));
                mx = fmaxf(mx, __shfl_xor(mx, 4));
                mx = fmaxf(mx, __shfl_xor(mx, 2));
                mx = fmaxf(mx, __shfl_xor(mx, 1));
                float p = __expf(ln - mx);
                float sm = p;
                sm += __shfl_xor(sm, 16);
                sm += __shfl_xor(sm, 8);
                sm += __shfl_xor(sm, 4);
                sm += __shfl_xor(sm, 2);
                sm += __shfl_xor(sm, 1);
                float r = (p / sm) * aoC;
                rs += r;
                #pragma unroll
                for (int e = 0; e < 16; ++e) {
                    float rv = r * va[e];
                    m1[e] += rv;
                    m2[e] = fmaf(rv, va[e], m2[e]);
                }
            }
        }

        // ---- reduce over g: in-wave pair reduce, then two-round LDS tree (16 KB buf)
        rs += __shfl_xor(rs, 32);
        #pragma unroll
        for (int e = 0; e < 16; ++e) m1[e] += __shfl_xor(m1[e], 32);
        #pragma unroll
        for (int e = 0; e < 16; ++e) m2[e] += __shfl_xor(m2[e], 32);

        if ((g & 1) == 0) {                       // round A: m1 + rs
            int gp = g >> 1;
            #pragma unroll
            for (int e = 0; e < 16; ++e) buf[gp][c][e ^ (c & 15)] = m1[e];
            rsp[gp][c] = rs;
        }
        __syncthreads();
        float M1 = 0.f, RS = 0.f;
        #pragma unroll
        for (int gp = 0; gp < 8; ++gp) M1 += buf[gp][oc][oe ^ (oc & 15)];
        #pragma unroll
        for (int gp = 0; gp < 8; ++gp) RS += rsp[gp][oc];
        __syncthreads();                          // m1 reads done before m2 overwrite
        if ((g & 1) == 0) {                       // round B: m2
            int gp = g >> 1;
            #pragma unroll
            for (int e = 0; e < 16; ++e) buf[gp][c][e ^ (c & 15)] = m2[e];
        }
        __syncthreads();
        float M2 = 0.f;
        #pragma unroll
        for (int gp = 0; gp < 8; ++gp) M2 += buf[gp][oc][oe ^ (oc & 15)];

        // ---- M-step in (oc, oe) view
        float inv = 1.0f / (RS + EPSL);
        float muv = M1 * inv;
        float s   = RS * inv;
        float sig = fmaf(-muv * muv, (2.0f - s), M2 * inv) + EPSL;
        float hl  = 0.5f * __logf(sig);
        hl += __shfl_xor(hl, 1);
        hl += __shfl_xor(hl, 2);
        hl += __shfl_xor(hl, 4);
        hl += __shfl_xor(hl, 8);
        float cost = RS * fmaf(16.0f, buC, hl);
        float ao   = 1.0f / (1.0f + __expf(-LAM * (baC - cost)));

        if (it == NITER - 1) {
            out[pos * 512 + t] = muv;                    // t == oc*16+oe
            if (oe == 0) out[MU_SZ + pos * 32 + oc] = ao;
        } else {
            mu_s[oc][oe ^ (oc & 15)] = muv;
            is_s[oc][oe ^ (oc & 15)] = 0.5f / sig;
            if (oe == 0) { cst_s[oc] = __logf(ao) - hl; ao_s[oc] = ao; }
            __syncthreads();                             // also orders M2 reads vs next write
            // back in (g,c) view: pull next-iteration E-state into registers
            #pragma unroll
            for (int e = 0; e < 16; ++e) muR[e] = mu_s[c][e ^ (c & 15)];
            #pragma unroll
            for (int e = 0; e < 16; ++e) isR[e] = is_s[c][e ^ (c & 15)];
            cstC = cst_s[c];
            aoC  = ao_s[c];
        }
    }
}

extern "C" void kernel_launch(void* const* d_in, const int* in_sizes, int n_in,
                              void* d_out, int out_size, void* d_ws, size_t ws_size,
                              hipStream_t stream) {
    const float* x  = (const float*)d_in[0];
    const float* a  = (const float*)d_in[1];
    const float* w  = (const float*)d_in[2];
    const float* bu = (const float*)d_in[3];
    const float* ba = (const float*)d_in[4];
    float* out = (float*)d_out;
    emcaps_kernel<<<NPOS, 512, 0, stream>>>(x, a, w, bu, ba, out);
}

// Round 5
// 180.814 us; speedup vs baseline: 3.2853x; 3.2853x over previous
//
#include <hip/hip_runtime.h>

#define C_OUT  32
#define PS     16
#define KB     288          // 3*3*32 input capsules per patch
#define NITER  3
#define EPSL   1e-6f
#define LAM    0.001f
#define OH     12
#define OW     12
#define NPOS   576          // 4*12*12
#define MU_SZ  (NPOS*C_OUT*PS)
#define NG     16           // k-groups (one per 32-lane half-wave)
#define KPG    (KB/NG)      // 18 k's per thread

// v[k,c,i,l] = sum_j xp[k,i,j] * w[k,c,j,l]  — full 4x4 matrix per (k,c) in registers.
__device__ __forceinline__ void compute_v(const float* __restrict__ xp,
                                          const float* __restrict__ w,
                                          int k, int c, float* __restrict__ va) {
    const float4* xk = (const float4*)(xp + (k << 4));
    float4 x0 = xk[0], x1 = xk[1], x2 = xk[2], x3 = xk[3];   // row i over j
    const float4* wr = (const float4*)(w + (((k << 5) + c) << 4));
    float4 w0 = wr[0], w1 = wr[1], w2 = wr[2], w3 = wr[3];   // row j over l
#define VROW(i, xi) \
    va[4*i+0] = fmaf(xi.x, w0.x, fmaf(xi.y, w1.x, fmaf(xi.z, w2.x, xi.w * w3.x))); \
    va[4*i+1] = fmaf(xi.x, w0.y, fmaf(xi.y, w1.y, fmaf(xi.z, w2.y, xi.w * w3.y))); \
    va[4*i+2] = fmaf(xi.x, w0.z, fmaf(xi.y, w1.z, fmaf(xi.z, w2.z, xi.w * w3.z))); \
    va[4*i+3] = fmaf(xi.x, w0.w, fmaf(xi.y, w1.w, fmaf(xi.z, w2.w, xi.w * w3.w)));
    VROW(0, x0) VROW(1, x1) VROW(2, x2) VROW(3, x3)
#undef VROW
}

// (512, 2): cap VGPR at 256 so the allocator takes what the dataflow needs
// (~112-130) with ZERO scratch spills. (512,6) forced 40 VGPR -> 1.5 GB spill
// traffic; even (512,4) made the compiler pick 64+spills. Total grid is only
// 4.5 waves/SIMD anyway — clean chains beat forced occupancy here.
__global__ __launch_bounds__(512, 2)
void emcaps_kernel(const float* __restrict__ x, const float* __restrict__ a,
                   const float* __restrict__ w, const float* __restrict__ beta_u,
                   const float* __restrict__ beta_a, float* __restrict__ out) {
    __shared__ __align__(16) float xp[KB * PS];   // 18 KB patch poses [k][16]
    __shared__ float a_lds[KB];                   // input activations (pre-scaled 1/C)
    __shared__ float buf[8][32][16];              // 16 KB: m1 partials, then m2 partials
    __shared__ float rsp[8][32];                  // partial r_sum
    __shared__ float mu_s[32][16];                // mu    [c][e ^ (c&15)]
    __shared__ float is_s[32][16];                // 0.5/sigma^2, same swizzle
    __shared__ float cst_s[32];                   // log(a_out) - sum_e 0.5 log sigma^2
    __shared__ float ao_s[32];                    // a_out

    const int t  = threadIdx.x;       // 512 threads
    const int g  = t >> 5;            // k-group 0..15  (E-step view)
    const int c  = t & 31;            // output capsule (E-step view)
    const int oc = t >> 4;            // capsule 0..31  (M-step view)
    const int oe = t & 15;            // pose elem      (M-step view)

    const int pos = blockIdx.x;
    const int bb  = pos / (OH * OW);
    const int rem = pos % (OH * OW);
    const int hh  = rem / OW;
    const int ww  = rem % OW;

    // ---- stage 3x3 patch into LDS (9 contiguous 2 KB rows, coalesced float4)
    const float4* x4  = (const float4*)x;
    float4*       xp4 = (float4*)xp;
    for (int u = t; u < KB * PS / 4; u += 512) {
        int pc = u >> 7, r = u & 127;
        int ki = pc / 3, kj = pc % 3;
        long src = (((long)(bb * 14 + hh + ki)) * 14 + (ww + kj)) * 128;
        xp4[u] = x4[src + r];
    }
    if (t < KB) {
        int pc = t >> 5, bi = t & 31;
        int ki = pc / 3, kj = pc % 3;
        a_lds[t] = a[(((bb * 14 + hh + ki)) * 14 + (ww + kj)) * 32 + bi] * (1.0f / C_OUT);
    }
    __syncthreads();

    const float buC = beta_u[oc];     // M-step view constants
    const float baC = beta_a[oc];

    float muR[16], isR[16];           // E-step per-c state (registers)
    float cstC = 0.f, aoC = 0.f;

    for (int it = 0; it < NITER; ++it) {
        float m1[16], m2[16], rs = 0.f;
        #pragma unroll
        for (int e = 0; e < 16; ++e) { m1[e] = 0.f; m2[e] = 0.f; }

        if (it == 0) {
            #pragma unroll 2
            for (int kk = 0; kk < KPG; ++kk) {
                int k = g * KPG + kk;
                float va[16];
                compute_v(xp, w, k, c, va);
                float r = a_lds[k];               // already scaled by 1/C
                rs += r;
                #pragma unroll
                for (int e = 0; e < 16; ++e) {
                    float rv = r * va[e];
                    m1[e] += rv;
                    m2[e] = fmaf(rv, va[e], m2[e]);
                }
            }
        } else {
            #pragma unroll 2
            for (int kk = 0; kk < KPG; ++kk) {
                int k = g * KPG + kk;
                float va[16];
                compute_v(xp, w, k, c, va);
                // ln-term: fully lane-local (no shuffles)
                float acc = 0.f;
                #pragma unroll
                for (int e = 0; e < 16; ++e) {
                    float d = va[e] - muR[e];
                    acc = fmaf(d * d, isR[e], acc);
                }
                float ln = cstC - acc;
                // softmax over c: 32-lane butterfly (lane bits 0..4)
                float mx = ln;
                mx = fmaxf(mx, __shfl_xor(mx, 16));
                mx = fmaxf(mx, __shfl_xor(mx, 8));
                mx = fmaxf(mx, __shfl_xor(mx, 4));
                mx = fmaxf(mx, __shfl_xor(mx, 2));
                mx = fmaxf(mx, __shfl_xor(mx, 1));
                float p = __expf(ln - mx);
                float sm = p;
                sm += __shfl_xor(sm, 16);
                sm += __shfl_xor(sm, 8);
                sm += __shfl_xor(sm, 4);
                sm += __shfl_xor(sm, 2);
                sm += __shfl_xor(sm, 1);
                float r = (p / sm) * aoC;
                rs += r;
                #pragma unroll
                for (int e = 0; e < 16; ++e) {
                    float rv = r * va[e];
                    m1[e] += rv;
                    m2[e] = fmaf(rv, va[e], m2[e]);
                }
            }
        }

        // ---- reduce over g: in-wave pair reduce, then two-round LDS tree (16 KB buf)
        rs += __shfl_xor(rs, 32);
        #pragma unroll
        for (int e = 0; e < 16; ++e) m1[e] += __shfl_xor(m1[e], 32);
        #pragma unroll
        for (int e = 0; e < 16; ++e) m2[e] += __shfl_xor(m2[e], 32);

        if ((g & 1) == 0) {                       // round A: m1 + rs
            int gp = g >> 1;
            #pragma unroll
            for (int e = 0; e < 16; ++e) buf[gp][c][e ^ (c & 15)] = m1[e];
            rsp[gp][c] = rs;
        }
        __syncthreads();
        float M1 = 0.f, RS = 0.f;
        #pragma unroll
        for (int gp = 0; gp < 8; ++gp) M1 += buf[gp][oc][oe ^ (oc & 15)];
        #pragma unroll
        for (int gp = 0; gp < 8; ++gp) RS += rsp[gp][oc];
        __syncthreads();                          // m1 reads done before m2 overwrite
        if ((g & 1) == 0) {                       // round B: m2
            int gp = g >> 1;
            #pragma unroll
            for (int e = 0; e < 16; ++e) buf[gp][c][e ^ (c & 15)] = m2[e];
        }
        __syncthreads();
        float M2 = 0.f;
        #pragma unroll
        for (int gp = 0; gp < 8; ++gp) M2 += buf[gp][oc][oe ^ (oc & 15)];

        // ---- M-step in (oc, oe) view
        float inv = 1.0f / (RS + EPSL);
        float muv = M1 * inv;
        float s   = RS * inv;
        float sig = fmaf(-muv * muv, (2.0f - s), M2 * inv) + EPSL;
        float hl  = 0.5f * __logf(sig);
        hl += __shfl_xor(hl, 1);
        hl += __shfl_xor(hl, 2);
        hl += __shfl_xor(hl, 4);
        hl += __shfl_xor(hl, 8);
        float cost = RS * fmaf(16.0f, buC, hl);
        float ao   = 1.0f / (1.0f + __expf(-LAM * (baC - cost)));

        if (it == NITER - 1) {
            out[pos * 512 + t] = muv;                    // t == oc*16+oe
            if (oe == 0) out[MU_SZ + pos * 32 + oc] = ao;
        } else {
            mu_s[oc][oe ^ (oc & 15)] = muv;
            is_s[oc][oe ^ (oc & 15)] = 0.5f / sig;
            if (oe == 0) { cst_s[oc] = __logf(ao) - hl; ao_s[oc] = ao; }
            __syncthreads();                             // also orders M2 reads vs next write
            // back in (g,c) view: pull next-iteration E-state into registers
            #pragma unroll
            for (int e = 0; e < 16; ++e) muR[e] = mu_s[c][e ^ (c & 15)];
            #pragma unroll
            for (int e = 0; e < 16; ++e) isR[e] = is_s[c][e ^ (c & 15)];
            cstC = cst_s[c];
            aoC  = ao_s[c];
        }
    }
}

extern "C" void kernel_launch(void* const* d_in, const int* in_sizes, int n_in,
                              void* d_out, int out_size, void* d_ws, size_t ws_size,
                              hipStream_t stream) {
    const float* x  = (const float*)d_in[0];
    const float* a  = (const float*)d_in[1];
    const float* w  = (const float*)d_in[2];
    const float* bu = (const float*)d_in[3];
    const float* ba = (const float*)d_in[4];
    float* out = (float*)d_out;
    emcaps_kernel<<<NPOS, 512, 0, stream>>>(x, a, w, bu, ba, out);
}